// Round 8
// baseline (1608.188 us; speedup 1.0000x reference)
//
#include <hip/hip_runtime.h>
#include <hip/hip_bf16.h>
#include <math.h>

// Problem constants (fixed by reference)
#define NB 4
#define NR 4096
#define NC 32
#define NH 256
#define NW 256
#define NS 48
#define NRAYS (NB*NR)          // 16384
#define NSAMP (NRAYS*NS)       // 786432

__device__ __forceinline__ float coarse_depth(int i) {
    const float DELTA = 1.05f / 47.f;
    return 2.25f + i * DELTA + 0.5f * DELTA;
}
__device__ __forceinline__ float zmid_c(int i) {
    return 0.5f * (coarse_depth(i) + coarse_depth(i + 1));
}
// fast softplus: max(x,0) + log(1+exp(-|x|)) via v_exp_f32/v_log_f32
__device__ __forceinline__ float softplus_f(float x) {
    return fmaxf(x, 0.f) + __logf(1.f + __expf(-fabsf(x)));
}
__device__ __forceinline__ float sigmoid_f(float x) {
    return __frcp_rn(1.f + __expf(-x));
}

// ---------------------------------------------------------------------------
// K0: transpose planes (B,3,C,H,W) -> channel-interleaved (B*3, H*W, C)
// ---------------------------------------------------------------------------
__global__ __launch_bounds__(256) void k_transpose(const float* __restrict__ in,
                                                   float* __restrict__ out) {
    __shared__ float tile[32][65];
    int bp = blockIdx.x >> 10;            // 0..11  (b*3+p)
    int t0 = (blockIdx.x & 1023) * 64;    // pixel base within 65536
    const float* src = in + (size_t)bp * NC * NH * NW;
    float* dst = out + (size_t)bp * NH * NW * NC;
    int px = threadIdx.x & 63;
    int c0 = threadIdx.x >> 6;            // 0..3
    #pragma unroll
    for (int cc = 0; cc < 32; cc += 4)
        tile[cc + c0][px] = src[(size_t)(cc + c0) * NH * NW + t0 + px];
    __syncthreads();
    int c = threadIdx.x & 31;
    int p0 = threadIdx.x >> 5;            // 0..7
    #pragma unroll
    for (int pp = 0; pp < 64; pp += 8)
        dst[(size_t)(t0 + pp + p0) * NC + c] = tile[c][pp + p0];
}

// ---------------------------------------------------------------------------
// K_prep: weight relayouts.
//  w1t [64][32]  : w1 transposed (row j = input weights of hidden j)
//  w2p [64][36]  : w2 rows padded 33->36 (v1 layout)
//  w2q [64][48]  : per-quad-lane 12-float slots (v2 layout)
//                  q=0: cols 0..8 (sigma+rgb0..7), q>=1: cols 8q+1..8q+8
//  bq  [48]      : b2 in the same quad layout
// ---------------------------------------------------------------------------
__global__ __launch_bounds__(256) void k_prep(const float* __restrict__ w1,
                                              const float* __restrict__ w2,
                                              const float* __restrict__ b2,
                                              float* __restrict__ w1t,
                                              float* __restrict__ w2p,
                                              float* __restrict__ w2q,
                                              float* __restrict__ bq) {
    for (int i = threadIdx.x; i < 2048; i += 256) {
        int j = i >> 5, c = i & 31;
        w1t[j * 32 + c] = w1[c * 64 + j];
    }
    for (int i = threadIdx.x; i < 64 * 36; i += 256) {
        int j = i / 36, kx = i - j * 36;
        w2p[i] = (kx < 33) ? w2[j * 33 + kx] : 0.f;
    }
    for (int i = threadIdx.x; i < 64 * 48; i += 256) {
        int j = i / 48, r = i - j * 48;
        int q = r / 12, kk = r - q * 12;
        int col; bool valid;
        if (q == 0) { col = kk;            valid = kk < 9; }
        else        { col = 8 * q + kk + 1; valid = kk < 8; }
        w2q[i] = valid ? w2[j * 33 + col] : 0.f;
    }
    if (threadIdx.x < 48) {
        int q = threadIdx.x / 12, kk = threadIdx.x - q * 12;
        int col; bool valid;
        if (q == 0) { col = kk;            valid = kk < 9; }
        else        { col = 8 * q + kk + 1; valid = kk < 8; }
        bq[threadIdx.x] = valid ? b2[col] : 0.f;
    }
}

// ---------------------------------------------------------------------------
// K1a/K3a: tri-plane gather (unchanged from R7).
// ---------------------------------------------------------------------------
template<bool FINE>
__global__ __launch_bounds__(256) void k_gather(
    const float* __restrict__ planes_t,
    const float* __restrict__ origins,
    const float* __restrict__ dirs,
    const float* __restrict__ dfine,       // null for coarse
    float* __restrict__ feats_out)         // [NSAMP][32]
{
    int lane  = threadIdx.x & 63;
    int wbase = threadIdx.x & 192;        // (tid>>6)*64: wave's sample base
    int s0    = blockIdx.x * 256 + wbase;

    // ---- phase 1: meta for OWN sample (registers) ----
    int s   = s0 + lane;
    int ray = s / NS;
    int kk  = s - ray * NS;
    float t = FINE ? dfine[s] : coarse_depth(kk);
    float ox = origins[ray*3+0], oy = origins[ray*3+1], oz = origins[ray*3+2];
    float ddx = dirs[ray*3+0],   ddy = dirs[ray*3+1],   ddz = dirs[ray*3+2];
    float cx = 2.f * (ox + t * ddx);
    float cy = 2.f * (oy + t * ddy);
    float cz = 2.f * (oz + t * ddz);
    int bi = ray >> 12;                   // /NR
    int   m_base[3];
    float m_q[3][4];
    #pragma unroll
    for (int p = 0; p < 3; ++p) {
        // plane0:(cx,cy)  plane1:(cx,cz)  plane2:(cz,cx)
        float gx = (p == 2) ? cz : cx;
        float gy = (p == 0) ? cy : ((p == 1) ? cz : cx);
        float fx = (gx + 1.f) * 128.f - 0.5f;
        float fy = (gy + 1.f) * 128.f - 0.5f;
        float x0f = floorf(fx), y0f = floorf(fy);
        float wx = fx - x0f, wy = fy - y0f;
        int x0 = (int)x0f, y0 = (int)y0f;
        if (x0 >= -1 && x0 <= 255 && y0 >= -1 && y0 <= 255) {
            float wxm = 1.f - wx, wym = 1.f - wy;
            float q00 = wxm*wym, q10 = wx*wym, q01 = wxm*wy, q11 = wx*wy;
            if (!(x0 >= 0   && y0 >= 0))   q00 = 0.f;
            if (!(x0 <= 254 && y0 >= 0))   q10 = 0.f;
            if (!(x0 >= 0   && y0 <= 254)) q01 = 0.f;
            if (!(x0 <= 254 && y0 <= 254)) q11 = 0.f;
            // guard region before planes_t absorbs x0=y0=-1 reads (x0 weight)
            m_base[p] = (bi*3 + p) * (NH*NW*NC) + (y0*NW + x0)*NC;
            m_q[p][0] = q00; m_q[p][1] = q10; m_q[p][2] = q01; m_q[p][3] = q11;
        } else {
            m_base[p] = -1;               // fully out: skip sentinel
            m_q[p][0] = m_q[p][1] = m_q[p][2] = m_q[p][3] = 0.f;
        }
    }

    // ---- phase 2: gather (2 samples/iter, half-wave lane=channel) ----
    int ch   = lane & 31;
    int half = lane >> 5;
    #pragma unroll 1
    for (int i = 0; i < 64; i += 2) {
        int src = i + half;               // meta source lane
        float acc = 0.f;
        #pragma unroll
        for (int p = 0; p < 3; ++p) {
            int   bse = __shfl(m_base[p], src);
            float q00 = __shfl(m_q[p][0], src);
            float q10 = __shfl(m_q[p][1], src);
            float q01 = __shfl(m_q[p][2], src);
            float q11 = __shfl(m_q[p][3], src);
            if (bse >= 0) {
                const float* ptr = planes_t + (size_t)bse + ch;
                acc += q00 * ptr[0]    + q10 * ptr[32]
                     + q01 * ptr[8192] + q11 * ptr[8224];
            }
        }
        feats_out[(size_t)(s0 + i + half) * 32 + ch] = acc * (1.f / 3.f);
    }
}

// ---------------------------------------------------------------------------
// K_mlp V1: thread-per-sample, waves_per_eu(3,5) -> occupancy TARGET <=5
// waves/EU so the allocator stops spilling to chase 8 waves (R6/R7: VGPR
// stuck at 44-48 < 74 live floats, scratch traffic in WRITE_SIZE).
// ---------------------------------------------------------------------------
__global__ __launch_bounds__(256)
__attribute__((amdgpu_waves_per_eu(3, 5)))
void k_mlp(
    const float* __restrict__ w1t,   // [64][32]
    const float* __restrict__ b1,
    const float* __restrict__ w2p,   // [64][36] (rows padded)
    const float* __restrict__ b2,
    float* __restrict__ rgb_io,      // in: feats, out: rgb
    float* __restrict__ sig_out)
{
    int s = blockIdx.x * 256 + threadIdx.x;
    float* base = rgb_io + (size_t)s * 32;
    float x[32];
    #pragma unroll
    for (int i = 0; i < 8; ++i) {
        float4 v = ((const float4*)base)[i];
        x[4*i+0] = v.x; x[4*i+1] = v.y; x[4*i+2] = v.z; x[4*i+3] = v.w;
    }
    float o[33];
    #pragma unroll
    for (int k2 = 0; k2 < 33; ++k2) o[k2] = b2[k2];
    #pragma unroll 4
    for (int j = 0; j < 64; ++j) {
        float a = b1[j];
        #pragma unroll
        for (int c = 0; c < 32; ++c) a += x[c] * w1t[j * 32 + c];
        float h = softplus_f(a);
        #pragma unroll
        for (int k2 = 0; k2 < 33; ++k2) o[k2] += h * w2p[j * 36 + k2];
    }
    sig_out[s] = o[0];
    #pragma unroll
    for (int i = 0; i < 8; ++i) {
        float4 r;
        r.x = sigmoid_f(o[1 + 4*i + 0]) * 1.002f - 0.001f;
        r.y = sigmoid_f(o[1 + 4*i + 1]) * 1.002f - 0.001f;
        r.z = sigmoid_f(o[1 + 4*i + 2]) * 1.002f - 0.001f;
        r.w = sigmoid_f(o[1 + 4*i + 3]) * 1.002f - 0.001f;
        ((float4*)base)[i] = r;
    }
}

// ---------------------------------------------------------------------------
// K_mlp V2: quad-per-sample. 4 consecutive lanes split one sample:
//  layer1: lane q computes h[j0..j0+15] (j0=q*16)  -> LDS (padded row 68)
//  layer2: each lane accumulates its 8-9 output cols from all 64 h.
// Peak live regs ~58 (x32+h16) -> no spill even at high occupancy.
// Same-wave LDS producer/consumer -> no barrier. Coalesced stores.
// FMA order identical to V1 (bitwise-same results).
// ---------------------------------------------------------------------------
__global__ __launch_bounds__(256)
__attribute__((amdgpu_waves_per_eu(4, 7)))
void k_mlp2(
    const float* __restrict__ w1t,   // [64][32]
    const float* __restrict__ b1,
    const float* __restrict__ w2q,   // [64][48] quad layout
    const float* __restrict__ bq,    // [48]
    float* __restrict__ rgb_io,      // in: feats, out: rgb
    float* __restrict__ sig_out)
{
    __shared__ float hs[64 * 68];    // 64 samples x (64 h + 4 pad)
    int q  = threadIdx.x & 3;
    int sl = threadIdx.x >> 2;       // local sample 0..63
    int s  = blockIdx.x * 64 + sl;
    const float* xp = rgb_io + (size_t)s * 32;
    float x[32];
    #pragma unroll
    for (int i = 0; i < 8; ++i) {
        float4 v = ((const float4*)xp)[i];
        x[4*i+0] = v.x; x[4*i+1] = v.y; x[4*i+2] = v.z; x[4*i+3] = v.w;
    }
    int j0 = q * 16;
    float h[16];
    #pragma unroll
    for (int jj = 0; jj < 16; ++jj) {
        int j = j0 + jj;
        float a = b1[j];
        #pragma unroll
        for (int c = 0; c < 32; ++c) a += x[c] * w1t[j * 32 + c];
        h[jj] = softplus_f(a);
    }
    float* hrow = hs + sl * 68 + j0;
    #pragma unroll
    for (int i = 0; i < 4; ++i)
        ((float4*)hrow)[i] = make_float4(h[4*i], h[4*i+1], h[4*i+2], h[4*i+3]);
    // producer and consumer are the same wave: lgkmcnt wait suffices (compiler)

    float o[9];
    #pragma unroll
    for (int kk = 0; kk < 9; ++kk) o[kk] = bq[q * 12 + kk];  // pad slots = 0
    const float* hbase = hs + sl * 68;
    #pragma unroll 4
    for (int j = 0; j < 64; ++j) {
        float hj = hbase[j];
        const float* wr = w2q + j * 48 + q * 12;
        #pragma unroll
        for (int kk = 0; kk < 9; ++kk) o[kk] += hj * wr[kk];
    }
    if (q == 0) sig_out[s] = o[0];
    float r[8];
    #pragma unroll
    for (int i = 0; i < 8; ++i) {
        float ov = (q == 0) ? o[i + 1] : o[i];
        r[i] = sigmoid_f(ov) * 1.002f - 0.001f;
    }
    float* outp = rgb_io + (size_t)s * 32 + q * 8;
    ((float4*)outp)[0] = make_float4(r[0], r[1], r[2], r[3]);
    ((float4*)outp)[1] = make_float4(r[4], r[5], r[6], r[7]);
}

// ---------------------------------------------------------------------------
// K2: coarse ray-march -> weights -> blur -> PDF -> 48 importance depths.
// ---------------------------------------------------------------------------
__global__ __launch_bounds__(256) void k_importance(const float* __restrict__ sig,
                                                    float* __restrict__ dfine) {
    int ray = blockIdx.x * 256 + threadIdx.x;
    const float* sp = sig + (size_t)ray * NS;
    float w[47];
    float T = 1.f;
    float sprev = sp[0];
    #pragma unroll
    for (int i = 0; i < 47; ++i) {
        float scur = sp[i + 1];
        float dens = softplus_f(0.5f * (sprev + scur) - 1.f);
        float delta = coarse_depth(i + 1) - coarse_depth(i);
        float alpha = 1.f - __expf(-dens * delta);
        w[i] = alpha * T + 0.01f;            // weights + 0.01
        T *= (1.f - alpha + 1e-10f);
        sprev = scur;
    }
    float p[45];
    float sum = 0.f;
    #pragma unroll
    for (int i = 1; i <= 45; ++i) {
        float nwi  = fmaxf(w[i - 1], w[i]);
        float nwi1 = fmaxf(w[i], w[i + 1]);
        float wb = 0.5f * (nwi + nwi1) + 0.01f;
        float v = wb + 1e-5f;
        p[i - 1] = v;
        sum += v;
    }
    int k = 0;
    float cdf_lo = 0.f;
    #pragma unroll
    for (int i = 0; i < 45; ++i) {
        float cdf_hi = cdf_lo + p[i] / sum;
        float bb = zmid_c(i), ba = zmid_c(i + 1);
        float denom = cdf_hi - cdf_lo;
        if (denom < 1e-5f) denom = 1.f;
        while (k < 48) {
            float u = (k + 0.5f) / 48.f;
            if (u < cdf_hi) {
                dfine[(size_t)ray * NS + k] = bb + (u - cdf_lo) / denom * (ba - bb);
                ++k;
            } else break;
        }
        cdf_lo = cdf_hi;
    }
    while (k < 48) {
        dfine[(size_t)ray * NS + k] = zmid_c(45);
        ++k;
    }
}

// ---------------------------------------------------------------------------
// K4: merge coarse+fine, background MLP, final ray-march (unchanged from R7).
// ---------------------------------------------------------------------------
__global__ __launch_bounds__(256) void k_final(
    const float* __restrict__ sig_c, const float* __restrict__ rgb_c,
    const float* __restrict__ sig_f, const float* __restrict__ rgb_f,
    const float* __restrict__ dfine,
    const float* __restrict__ dirs, const float* __restrict__ z_bg,
    const float* __restrict__ bw1, const float* __restrict__ bb1,
    const float* __restrict__ bw2, const float* __restrict__ bb2,
    float* __restrict__ out_rgb, float* __restrict__ out_dep,
    float* __restrict__ out_wt)
{
    __shared__ float s_d[4][96];
    __shared__ float s_sig[4][96];
    __shared__ int   s_src[4][96];
    __shared__ float s_fine[4][48];
    __shared__ float s_w[4][96];
    __shared__ float s_g[4][96];
    __shared__ float s_h[4][64];
    __shared__ float s_zb[64];
    int lane = threadIdx.x & 63;
    int wv = threadIdx.x >> 6;
    int ray = blockIdx.x * 4 + wv;
    int bi = (blockIdx.x * 4) >> 12;
    if (threadIdx.x < 64) s_zb[threadIdx.x] = z_bg[bi * 64 + threadIdx.x];
    if (lane < 48) s_fine[wv][lane] = dfine[(size_t)ray * NS + lane];
    __syncthreads();

    if (lane < 48) {
        float cd = coarse_depth(lane);
        int lo = 0, hi = 48;
        while (lo < hi) { int mid = (lo + hi) >> 1;
            if (s_fine[wv][mid] < cd) lo = mid + 1; else hi = mid; }
        int rc = lane + lo;
        s_d[wv][rc] = cd;
        s_sig[wv][rc] = sig_c[(size_t)ray * NS + lane];
        s_src[wv][rc] = lane;
        float f = s_fine[wv][lane];
        lo = 0; hi = 48;
        while (lo < hi) { int mid = (lo + hi) >> 1;
            if (coarse_depth(mid) <= f) lo = mid + 1; else hi = mid; }
        int rf = lane + lo;
        s_d[wv][rf] = f;
        s_sig[wv][rf] = sig_f[(size_t)ray * NS + lane];
        s_src[wv][rf] = 48 + lane;
    }
    float ddx = dirs[ray*3+0], ddy = dirs[ray*3+1], ddz = dirs[ray*3+2];
    __syncthreads();

    float alpha0 = 0.f, alpha1 = 0.f, a0 = 1.f, a1 = 1.f;
    float dm0 = 0.f, dm1 = 0.f;
    if (lane < 48) {
        int i0 = 2 * lane, i1 = i0 + 1;
        float d0 = s_d[wv][i0], sA = s_sig[wv][i0];
        float d1 = s_d[wv][i1], sB = s_sig[wv][i1];
        {
            float dens = softplus_f(0.5f * (sA + sB) - 1.f);
            alpha0 = 1.f - __expf(-dens * (d1 - d0));
            a0 = 1.f - alpha0 + 1e-10f;
            dm0 = 0.5f * (d0 + d1);
        }
        if (i1 < 95) {
            float d2 = s_d[wv][i1 + 1], sC = s_sig[wv][i1 + 1];
            float dens = softplus_f(0.5f * (sB + sC) - 1.f);
            alpha1 = 1.f - __expf(-dens * (d2 - d1));
            a1 = 1.f - alpha1 + 1e-10f;
            dm1 = 0.5f * (d1 + d2);
        }
    }
    float P = a0 * a1;
    #pragma unroll
    for (int off = 1; off < 64; off <<= 1) {
        float t = __shfl_up(P, off);
        if (lane >= off) P *= t;
    }
    float T_all = __shfl(P, 63);
    float E = __shfl_up(P, 1);
    if (lane == 0) E = 1.f;
    float w0 = alpha0 * E;
    float w1 = alpha1 * (E * a0);
    float sw = w0 + w1;
    float sd = w0 * dm0 + w1 * dm1;
    #pragma unroll
    for (int off = 32; off; off >>= 1) {
        sw += __shfl_xor(sw, off);
        sd += __shfl_xor(sd, off);
    }
    if (lane < 48) {
        s_w[wv][2 * lane] = w0;
        s_w[wv][2 * lane + 1] = w1;
    }
    __syncthreads();
    {
        int i = lane;
        float wm = (i > 0) ? s_w[wv][i - 1] : 0.f;
        s_g[wv][i] = 0.5f * (wm + s_w[wv][i]);
        int i2 = lane + 64;
        if (lane < 32)
            s_g[wv][i2] = 0.5f * (s_w[wv][i2 - 1] + s_w[wv][i2]);
    }

    float a = bb1[lane] + ddx * bw1[lane] + ddy * bw1[64 + lane] + ddz * bw1[128 + lane];
    #pragma unroll 1
    for (int i = 0; i < 64; ++i) a += s_zb[i] * bw1[(3 + i) * 64 + lane];
    s_h[wv][lane] = softplus_f(a);
    __syncthreads();
    int c = lane & 31;
    float ob = bb2[c];
    #pragma unroll 1
    for (int j = 0; j < 64; ++j) ob += s_h[wv][j] * bw2[j * 32 + c];
    float bgc = sigmoid_f(ob);

    int h = lane >> 5;
    size_t rbase = (size_t)ray * NS * 32;
    const float* b0p = rgb_c + rbase;
    const float* b1p = rgb_f + rbase - (size_t)48 * 32;
    float acc = 0.f;
    #pragma unroll 4
    for (int i = h; i < 96; i += 2) {
        int src = s_src[wv][i];
        const float* cp = ((src < 48) ? b0p : b1p) + (size_t)src * 32;
        acc += s_g[wv][i] * cp[c];
    }
    acc += __shfl_xor(acc, 32);

    float rgbv = (acc + T_all * bgc) * 2.f - 1.f;
    float dep = sd / sw;
    if (!(dep == dep)) dep = INFINITY;
    dep = fminf(fmaxf(dep, coarse_depth(0)), coarse_depth(47));
    if (lane < 32) out_rgb[(size_t)ray * 32 + c] = rgbv;
    if (lane == 0) { out_dep[ray] = dep; out_wt[ray] = sw; }
}

// ---------------------------------------------------------------------------
extern "C" void kernel_launch(void* const* d_in, const int* in_sizes, int n_in,
                              void* d_out, int out_size, void* d_ws, size_t ws_size,
                              hipStream_t stream) {
    (void)in_sizes; (void)n_in; (void)out_size; (void)ws_size;
    const float* planes  = (const float*)d_in[0];
    const float* origins = (const float*)d_in[1];
    const float* dirs    = (const float*)d_in[2];
    const float* z_bg    = (const float*)d_in[3];
    const float* dw1     = (const float*)d_in[4];
    const float* db1     = (const float*)d_in[5];
    const float* dw2     = (const float*)d_in[6];
    const float* db2     = (const float*)d_in[7];
    const float* bw1     = (const float*)d_in[8];
    const float* bb1     = (const float*)d_in[9];
    const float* bw2     = (const float*)d_in[10];
    const float* bb2     = (const float*)d_in[11];

    // workspace layout (f32), ~311 MiB total.
    // Small buffers FIRST so planes_t has a ~9MB guard region before it
    // (boundary taps with zeroed weights may read up to ~33KB before a plane).
    char* ws = (char*)d_ws;
    size_t off = 0;
    float* sig_c    = (float*)(ws + off); off += (size_t)NSAMP * 4;
    float* sig_f    = (float*)(ws + off); off += (size_t)NSAMP * 4;
    float* dfine    = (float*)(ws + off); off += (size_t)NSAMP * 4;
    float* w1t      = (float*)(ws + off); off += 64 * 32 * 4;
    float* w2p      = (float*)(ws + off); off += 64 * 36 * 4;
    float* w2q      = (float*)(ws + off); off += 64 * 48 * 4;
    float* bq       = (float*)(ws + off); off += 256;
    float* planes_t = (float*)(ws + off); off += (size_t)NB * 3 * NH * NW * NC * 4;
    float* rgb_c    = (float*)(ws + off); off += (size_t)NSAMP * 32 * 4;
    float* rgb_f    = (float*)(ws + off); off += (size_t)NSAMP * 32 * 4;

    float* out_rgb = (float*)d_out;
    float* out_dep = out_rgb + (size_t)NRAYS * 32;
    float* out_wt  = out_dep + NRAYS;

    k_prep<<<dim3(1), dim3(256), 0, stream>>>(dw1, dw2, db2, w1t, w2p, w2q, bq);
    k_transpose<<<dim3(NB * 3 * 1024), dim3(256), 0, stream>>>(planes, planes_t);
    // coarse: gather feats into rgb_c, MLP V1 in-place (A/B arm 1)
    k_gather<false><<<dim3(NSAMP / 256), dim3(256), 0, stream>>>(
        planes_t, origins, dirs, (const float*)nullptr, rgb_c);
    k_mlp<<<dim3(NSAMP / 256), dim3(256), 0, stream>>>(
        w1t, db1, w2p, db2, rgb_c, sig_c);
    k_importance<<<dim3(NRAYS / 256), dim3(256), 0, stream>>>(sig_c, dfine);
    // fine: gather feats into rgb_f, MLP V2 quad-per-sample (A/B arm 2)
    k_gather<true><<<dim3(NSAMP / 256), dim3(256), 0, stream>>>(
        planes_t, origins, dirs, dfine, rgb_f);
    k_mlp2<<<dim3(NSAMP / 64), dim3(256), 0, stream>>>(
        w1t, db1, w2q, bq, rgb_f, sig_f);
    k_final<<<dim3(NRAYS / 4), dim3(256), 0, stream>>>(
        sig_c, rgb_c, sig_f, rgb_f, dfine, dirs, z_bg,
        bw1, bb1, bw2, bb2, out_rgb, out_dep, out_wt);
}

// Round 9
// 1037.770 us; speedup vs baseline: 1.5497x; 1.5497x over previous
//
#include <hip/hip_runtime.h>
#include <hip/hip_bf16.h>
#include <math.h>

// Problem constants (fixed by reference)
#define NB 4
#define NR 4096
#define NC 32
#define NH 256
#define NW 256
#define NS 48
#define NRAYS (NB*NR)          // 16384
#define NSAMP (NRAYS*NS)       // 786432

__device__ __forceinline__ float coarse_depth(int i) {
    const float DELTA = 1.05f / 47.f;
    return 2.25f + i * DELTA + 0.5f * DELTA;
}
__device__ __forceinline__ float zmid_c(int i) {
    return 0.5f * (coarse_depth(i) + coarse_depth(i + 1));
}
// fast softplus: max(x,0) + log(1+exp(-|x|)) via v_exp_f32/v_log_f32
__device__ __forceinline__ float softplus_f(float x) {
    return fmaxf(x, 0.f) + __logf(1.f + __expf(-fabsf(x)));
}
__device__ __forceinline__ float sigmoid_f(float x) {
    return __frcp_rn(1.f + __expf(-x));
}

// ---------------------------------------------------------------------------
// K0: transpose planes (B,3,C,H,W) -> channel-interleaved (B*3, H*W, C)
// ---------------------------------------------------------------------------
__global__ __launch_bounds__(256) void k_transpose(const float* __restrict__ in,
                                                   float* __restrict__ out) {
    __shared__ float tile[32][65];
    int bp = blockIdx.x >> 10;            // 0..11  (b*3+p)
    int t0 = (blockIdx.x & 1023) * 64;    // pixel base within 65536
    const float* src = in + (size_t)bp * NC * NH * NW;
    float* dst = out + (size_t)bp * NH * NW * NC;
    int px = threadIdx.x & 63;
    int c0 = threadIdx.x >> 6;            // 0..3
    #pragma unroll
    for (int cc = 0; cc < 32; cc += 4)
        tile[cc + c0][px] = src[(size_t)(cc + c0) * NH * NW + t0 + px];
    __syncthreads();
    int c = threadIdx.x & 31;
    int p0 = threadIdx.x >> 5;            // 0..7
    #pragma unroll
    for (int pp = 0; pp < 64; pp += 8)
        dst[(size_t)(t0 + pp + p0) * NC + c] = tile[c][pp + p0];
}

// ---------------------------------------------------------------------------
// K_prep: weight relayouts.
//  w1t [64][32] : w1 transposed (row j = input weights of hidden j)
//  w2p [64][36] : w2 rows padded 33->36 (V1 layout)
//  w2s [64][40] : pair layout. Per row j: slot block e*20 for lane parity e.
//     e=0: k=0 -> w2[j][0] (sigma), k=1..16 -> w2[j][1..16]  (rgb0..15)
//     e=1: k=0 -> 0 (dummy),       k=1..16 -> w2[j][17..32]  (rgb16..31)
//  bq2 [40]     : b2 in the same pair layout
// ---------------------------------------------------------------------------
__global__ __launch_bounds__(256) void k_prep(const float* __restrict__ w1,
                                              const float* __restrict__ w2,
                                              const float* __restrict__ b2,
                                              float* __restrict__ w1t,
                                              float* __restrict__ w2p,
                                              float* __restrict__ w2s,
                                              float* __restrict__ bq2) {
    for (int i = threadIdx.x; i < 2048; i += 256) {
        int j = i >> 5, c = i & 31;
        w1t[j * 32 + c] = w1[c * 64 + j];
    }
    for (int i = threadIdx.x; i < 64 * 36; i += 256) {
        int j = i / 36, kx = i - j * 36;
        w2p[i] = (kx < 33) ? w2[j * 33 + kx] : 0.f;
    }
    for (int i = threadIdx.x; i < 64 * 40; i += 256) {
        int j = i / 40, r = i - j * 40;
        int e = r / 20, k = r - e * 20;
        float v = 0.f;
        if (e == 0) { if (k < 17) v = w2[j * 33 + k]; }
        else        { if (k >= 1 && k < 17) v = w2[j * 33 + 16 + k]; }
        w2s[i] = v;
    }
    if (threadIdx.x < 40) {
        int e = threadIdx.x / 20, k = threadIdx.x - e * 20;
        float v = 0.f;
        if (e == 0) { if (k < 17) v = b2[k]; }
        else        { if (k >= 1 && k < 17) v = b2[16 + k]; }
        bq2[threadIdx.x] = v;
    }
}

// ---------------------------------------------------------------------------
// K1a/K3a: tri-plane gather (unchanged).
// ---------------------------------------------------------------------------
template<bool FINE>
__global__ __launch_bounds__(256) void k_gather(
    const float* __restrict__ planes_t,
    const float* __restrict__ origins,
    const float* __restrict__ dirs,
    const float* __restrict__ dfine,       // null for coarse
    float* __restrict__ feats_out)         // [NSAMP][32]
{
    int lane  = threadIdx.x & 63;
    int wbase = threadIdx.x & 192;        // (tid>>6)*64: wave's sample base
    int s0    = blockIdx.x * 256 + wbase;

    // ---- phase 1: meta for OWN sample (registers) ----
    int s   = s0 + lane;
    int ray = s / NS;
    int kk  = s - ray * NS;
    float t = FINE ? dfine[s] : coarse_depth(kk);
    float ox = origins[ray*3+0], oy = origins[ray*3+1], oz = origins[ray*3+2];
    float ddx = dirs[ray*3+0],   ddy = dirs[ray*3+1],   ddz = dirs[ray*3+2];
    float cx = 2.f * (ox + t * ddx);
    float cy = 2.f * (oy + t * ddy);
    float cz = 2.f * (oz + t * ddz);
    int bi = ray >> 12;                   // /NR
    int   m_base[3];
    float m_q[3][4];
    #pragma unroll
    for (int p = 0; p < 3; ++p) {
        // plane0:(cx,cy)  plane1:(cx,cz)  plane2:(cz,cx)
        float gx = (p == 2) ? cz : cx;
        float gy = (p == 0) ? cy : ((p == 1) ? cz : cx);
        float fx = (gx + 1.f) * 128.f - 0.5f;
        float fy = (gy + 1.f) * 128.f - 0.5f;
        float x0f = floorf(fx), y0f = floorf(fy);
        float wx = fx - x0f, wy = fy - y0f;
        int x0 = (int)x0f, y0 = (int)y0f;
        if (x0 >= -1 && x0 <= 255 && y0 >= -1 && y0 <= 255) {
            float wxm = 1.f - wx, wym = 1.f - wy;
            float q00 = wxm*wym, q10 = wx*wym, q01 = wxm*wy, q11 = wx*wy;
            if (!(x0 >= 0   && y0 >= 0))   q00 = 0.f;
            if (!(x0 <= 254 && y0 >= 0))   q10 = 0.f;
            if (!(x0 >= 0   && y0 <= 254)) q01 = 0.f;
            if (!(x0 <= 254 && y0 <= 254)) q11 = 0.f;
            // guard region before planes_t absorbs x0=y0=-1 reads (x0 weight)
            m_base[p] = (bi*3 + p) * (NH*NW*NC) + (y0*NW + x0)*NC;
            m_q[p][0] = q00; m_q[p][1] = q10; m_q[p][2] = q01; m_q[p][3] = q11;
        } else {
            m_base[p] = -1;               // fully out: skip sentinel
            m_q[p][0] = m_q[p][1] = m_q[p][2] = m_q[p][3] = 0.f;
        }
    }

    // ---- phase 2: gather (2 samples/iter, half-wave lane=channel) ----
    int ch   = lane & 31;
    int half = lane >> 5;
    #pragma unroll 1
    for (int i = 0; i < 64; i += 2) {
        int src = i + half;               // meta source lane
        float acc = 0.f;
        #pragma unroll
        for (int p = 0; p < 3; ++p) {
            int   bse = __shfl(m_base[p], src);
            float q00 = __shfl(m_q[p][0], src);
            float q10 = __shfl(m_q[p][1], src);
            float q01 = __shfl(m_q[p][2], src);
            float q11 = __shfl(m_q[p][3], src);
            if (bse >= 0) {
                const float* ptr = planes_t + (size_t)bse + ch;
                acc += q00 * ptr[0]    + q10 * ptr[32]
                     + q01 * ptr[8192] + q11 * ptr[8224];
            }
        }
        feats_out[(size_t)(s0 + i + half) * 32 + ch] = acc * (1.f / 3.f);
    }
}

// ---------------------------------------------------------------------------
// K_mlp V1: thread-per-sample (R7 config, known 160us). Fine pass / A/B ref.
// ---------------------------------------------------------------------------
__global__ __launch_bounds__(256)
__attribute__((amdgpu_waves_per_eu(3, 5)))
void k_mlp(
    const float* __restrict__ w1t,   // [64][32]
    const float* __restrict__ b1,
    const float* __restrict__ w2p,   // [64][36] (rows padded)
    const float* __restrict__ b2,
    float* __restrict__ rgb_io,      // in: feats, out: rgb
    float* __restrict__ sig_out)
{
    int s = blockIdx.x * 256 + threadIdx.x;
    float* base = rgb_io + (size_t)s * 32;
    float x[32];
    #pragma unroll
    for (int i = 0; i < 8; ++i) {
        float4 v = ((const float4*)base)[i];
        x[4*i+0] = v.x; x[4*i+1] = v.y; x[4*i+2] = v.z; x[4*i+3] = v.w;
    }
    float o[33];
    #pragma unroll
    for (int k2 = 0; k2 < 33; ++k2) o[k2] = b2[k2];
    #pragma unroll 4
    for (int j = 0; j < 64; ++j) {
        float a = b1[j];
        #pragma unroll
        for (int c = 0; c < 32; ++c) a += x[c] * w1t[j * 32 + c];
        float h = softplus_f(a);
        #pragma unroll
        for (int k2 = 0; k2 < 33; ++k2) o[k2] += h * w2p[j * 36 + k2];
    }
    sig_out[s] = o[0];
    #pragma unroll
    for (int i = 0; i < 8; ++i) {
        float4 r;
        r.x = sigmoid_f(o[1 + 4*i + 0]) * 1.002f - 0.001f;
        r.y = sigmoid_f(o[1 + 4*i + 1]) * 1.002f - 0.001f;
        r.z = sigmoid_f(o[1 + 4*i + 2]) * 1.002f - 0.001f;
        r.w = sigmoid_f(o[1 + 4*i + 3]) * 1.002f - 0.001f;
        ((float4*)base)[i] = r;
    }
}

// ---------------------------------------------------------------------------
// K_mlp PAIR (A/B arm, coarse pass): 2 consecutive lanes per sample.
// Lane parity e owns input half x[16e..16e+16) and output slot-block e:
//   e=0: {sigma, rgb0..15}, e=1: {dummy, rgb16..31}  (uniform o[17] layout,
//   all indexing compile-time static -> no scratch, no divergent FMA paths).
// Layer1 dot completed by one __shfl_xor(partial,1) per hidden unit.
// Live set ~45 floats -> fits the ~48 VGPRs the allocator insists on
// (R6-R8: attribute hints ignored, VGPR pinned 40-48, spill when live>budget).
// ---------------------------------------------------------------------------
__global__ __launch_bounds__(256) void k_mlp_pair(
    const float* __restrict__ w1t,   // [64][32]
    const float* __restrict__ b1,
    const float* __restrict__ w2s,   // [64][40] pair layout
    const float* __restrict__ bq2,   // [40]
    float* __restrict__ rgb_io,      // in: feats, out: rgb
    float* __restrict__ sig_out)
{
    int t = blockIdx.x * 256 + threadIdx.x;
    int s = t >> 1;
    int e = t & 1;
    float* xp = rgb_io + (size_t)s * 32 + e * 16;
    float x[16];
    #pragma unroll
    for (int i = 0; i < 4; ++i) {
        float4 v = ((const float4*)xp)[i];
        x[4*i+0] = v.x; x[4*i+1] = v.y; x[4*i+2] = v.z; x[4*i+3] = v.w;
    }
    const float* bb = bq2 + e * 20;
    float o[17];
    #pragma unroll
    for (int k = 0; k < 17; ++k) o[k] = bb[k];
    const float* w1base = w1t + e * 16;
    const float* w2base = w2s + e * 20;
    #pragma unroll 4
    for (int j = 0; j < 64; ++j) {
        float a = 0.f;
        #pragma unroll
        for (int c = 0; c < 16; ++c) a += x[c] * w1base[j * 32 + c];
        a += __shfl_xor(a, 1);           // pair sum -> full dot
        float h = softplus_f(a + b1[j]);
        #pragma unroll
        for (int k = 0; k < 17; ++k) o[k] += h * w2base[j * 40 + k];
    }
    if (e == 0) sig_out[s] = o[0];
    #pragma unroll
    for (int i = 0; i < 4; ++i) {
        float4 r;
        r.x = sigmoid_f(o[1 + 4*i + 0]) * 1.002f - 0.001f;
        r.y = sigmoid_f(o[1 + 4*i + 1]) * 1.002f - 0.001f;
        r.z = sigmoid_f(o[1 + 4*i + 2]) * 1.002f - 0.001f;
        r.w = sigmoid_f(o[1 + 4*i + 3]) * 1.002f - 0.001f;
        ((float4*)xp)[i] = r;            // own 64B half: read-before-write safe
    }
}

// ---------------------------------------------------------------------------
// K2: coarse ray-march -> weights -> blur -> PDF -> 48 importance depths.
// ---------------------------------------------------------------------------
__global__ __launch_bounds__(256) void k_importance(const float* __restrict__ sig,
                                                    float* __restrict__ dfine) {
    int ray = blockIdx.x * 256 + threadIdx.x;
    const float* sp = sig + (size_t)ray * NS;
    float w[47];
    float T = 1.f;
    float sprev = sp[0];
    #pragma unroll
    for (int i = 0; i < 47; ++i) {
        float scur = sp[i + 1];
        float dens = softplus_f(0.5f * (sprev + scur) - 1.f);
        float delta = coarse_depth(i + 1) - coarse_depth(i);
        float alpha = 1.f - __expf(-dens * delta);
        w[i] = alpha * T + 0.01f;            // weights + 0.01
        T *= (1.f - alpha + 1e-10f);
        sprev = scur;
    }
    float p[45];
    float sum = 0.f;
    #pragma unroll
    for (int i = 1; i <= 45; ++i) {
        float nwi  = fmaxf(w[i - 1], w[i]);
        float nwi1 = fmaxf(w[i], w[i + 1]);
        float wb = 0.5f * (nwi + nwi1) + 0.01f;
        float v = wb + 1e-5f;
        p[i - 1] = v;
        sum += v;
    }
    int k = 0;
    float cdf_lo = 0.f;
    #pragma unroll
    for (int i = 0; i < 45; ++i) {
        float cdf_hi = cdf_lo + p[i] / sum;
        float bb = zmid_c(i), ba = zmid_c(i + 1);
        float denom = cdf_hi - cdf_lo;
        if (denom < 1e-5f) denom = 1.f;
        while (k < 48) {
            float u = (k + 0.5f) / 48.f;
            if (u < cdf_hi) {
                dfine[(size_t)ray * NS + k] = bb + (u - cdf_lo) / denom * (ba - bb);
                ++k;
            } else break;
        }
        cdf_lo = cdf_hi;
    }
    while (k < 48) {
        dfine[(size_t)ray * NS + k] = zmid_c(45);
        ++k;
    }
}

// ---------------------------------------------------------------------------
// K4: merge coarse+fine, background MLP, final ray-march (unchanged).
// ---------------------------------------------------------------------------
__global__ __launch_bounds__(256) void k_final(
    const float* __restrict__ sig_c, const float* __restrict__ rgb_c,
    const float* __restrict__ sig_f, const float* __restrict__ rgb_f,
    const float* __restrict__ dfine,
    const float* __restrict__ dirs, const float* __restrict__ z_bg,
    const float* __restrict__ bw1, const float* __restrict__ bb1,
    const float* __restrict__ bw2, const float* __restrict__ bb2,
    float* __restrict__ out_rgb, float* __restrict__ out_dep,
    float* __restrict__ out_wt)
{
    __shared__ float s_d[4][96];
    __shared__ float s_sig[4][96];
    __shared__ int   s_src[4][96];
    __shared__ float s_fine[4][48];
    __shared__ float s_w[4][96];
    __shared__ float s_g[4][96];
    __shared__ float s_h[4][64];
    __shared__ float s_zb[64];
    int lane = threadIdx.x & 63;
    int wv = threadIdx.x >> 6;
    int ray = blockIdx.x * 4 + wv;
    int bi = (blockIdx.x * 4) >> 12;
    if (threadIdx.x < 64) s_zb[threadIdx.x] = z_bg[bi * 64 + threadIdx.x];
    if (lane < 48) s_fine[wv][lane] = dfine[(size_t)ray * NS + lane];
    __syncthreads();

    if (lane < 48) {
        float cd = coarse_depth(lane);
        int lo = 0, hi = 48;
        while (lo < hi) { int mid = (lo + hi) >> 1;
            if (s_fine[wv][mid] < cd) lo = mid + 1; else hi = mid; }
        int rc = lane + lo;
        s_d[wv][rc] = cd;
        s_sig[wv][rc] = sig_c[(size_t)ray * NS + lane];
        s_src[wv][rc] = lane;
        float f = s_fine[wv][lane];
        lo = 0; hi = 48;
        while (lo < hi) { int mid = (lo + hi) >> 1;
            if (coarse_depth(mid) <= f) lo = mid + 1; else hi = mid; }
        int rf = lane + lo;
        s_d[wv][rf] = f;
        s_sig[wv][rf] = sig_f[(size_t)ray * NS + lane];
        s_src[wv][rf] = 48 + lane;
    }
    float ddx = dirs[ray*3+0], ddy = dirs[ray*3+1], ddz = dirs[ray*3+2];
    __syncthreads();

    float alpha0 = 0.f, alpha1 = 0.f, a0 = 1.f, a1 = 1.f;
    float dm0 = 0.f, dm1 = 0.f;
    if (lane < 48) {
        int i0 = 2 * lane, i1 = i0 + 1;
        float d0 = s_d[wv][i0], sA = s_sig[wv][i0];
        float d1 = s_d[wv][i1], sB = s_sig[wv][i1];
        {
            float dens = softplus_f(0.5f * (sA + sB) - 1.f);
            alpha0 = 1.f - __expf(-dens * (d1 - d0));
            a0 = 1.f - alpha0 + 1e-10f;
            dm0 = 0.5f * (d0 + d1);
        }
        if (i1 < 95) {
            float d2 = s_d[wv][i1 + 1], sC = s_sig[wv][i1 + 1];
            float dens = softplus_f(0.5f * (sB + sC) - 1.f);
            alpha1 = 1.f - __expf(-dens * (d2 - d1));
            a1 = 1.f - alpha1 + 1e-10f;
            dm1 = 0.5f * (d1 + d2);
        }
    }
    float P = a0 * a1;
    #pragma unroll
    for (int off = 1; off < 64; off <<= 1) {
        float t = __shfl_up(P, off);
        if (lane >= off) P *= t;
    }
    float T_all = __shfl(P, 63);
    float E = __shfl_up(P, 1);
    if (lane == 0) E = 1.f;
    float w0 = alpha0 * E;
    float w1 = alpha1 * (E * a0);
    float sw = w0 + w1;
    float sd = w0 * dm0 + w1 * dm1;
    #pragma unroll
    for (int off = 32; off; off >>= 1) {
        sw += __shfl_xor(sw, off);
        sd += __shfl_xor(sd, off);
    }
    if (lane < 48) {
        s_w[wv][2 * lane] = w0;
        s_w[wv][2 * lane + 1] = w1;
    }
    __syncthreads();
    {
        int i = lane;
        float wm = (i > 0) ? s_w[wv][i - 1] : 0.f;
        s_g[wv][i] = 0.5f * (wm + s_w[wv][i]);
        int i2 = lane + 64;
        if (lane < 32)
            s_g[wv][i2] = 0.5f * (s_w[wv][i2 - 1] + s_w[wv][i2]);
    }

    float a = bb1[lane] + ddx * bw1[lane] + ddy * bw1[64 + lane] + ddz * bw1[128 + lane];
    #pragma unroll 1
    for (int i = 0; i < 64; ++i) a += s_zb[i] * bw1[(3 + i) * 64 + lane];
    s_h[wv][lane] = softplus_f(a);
    __syncthreads();
    int c = lane & 31;
    float ob = bb2[c];
    #pragma unroll 1
    for (int j = 0; j < 64; ++j) ob += s_h[wv][j] * bw2[j * 32 + c];
    float bgc = sigmoid_f(ob);

    int h = lane >> 5;
    size_t rbase = (size_t)ray * NS * 32;
    const float* b0p = rgb_c + rbase;
    const float* b1p = rgb_f + rbase - (size_t)48 * 32;
    float acc = 0.f;
    #pragma unroll 4
    for (int i = h; i < 96; i += 2) {
        int src = s_src[wv][i];
        const float* cp = ((src < 48) ? b0p : b1p) + (size_t)src * 32;
        acc += s_g[wv][i] * cp[c];
    }
    acc += __shfl_xor(acc, 32);

    float rgbv = (acc + T_all * bgc) * 2.f - 1.f;
    float dep = sd / sw;
    if (!(dep == dep)) dep = INFINITY;
    dep = fminf(fmaxf(dep, coarse_depth(0)), coarse_depth(47));
    if (lane < 32) out_rgb[(size_t)ray * 32 + c] = rgbv;
    if (lane == 0) { out_dep[ray] = dep; out_wt[ray] = sw; }
}

// ---------------------------------------------------------------------------
extern "C" void kernel_launch(void* const* d_in, const int* in_sizes, int n_in,
                              void* d_out, int out_size, void* d_ws, size_t ws_size,
                              hipStream_t stream) {
    (void)in_sizes; (void)n_in; (void)out_size; (void)ws_size;
    const float* planes  = (const float*)d_in[0];
    const float* origins = (const float*)d_in[1];
    const float* dirs    = (const float*)d_in[2];
    const float* z_bg    = (const float*)d_in[3];
    const float* dw1     = (const float*)d_in[4];
    const float* db1     = (const float*)d_in[5];
    const float* dw2     = (const float*)d_in[6];
    const float* db2     = (const float*)d_in[7];
    const float* bw1     = (const float*)d_in[8];
    const float* bb1     = (const float*)d_in[9];
    const float* bw2     = (const float*)d_in[10];
    const float* bb2     = (const float*)d_in[11];

    // workspace layout (f32), ~311 MiB total.
    // Small buffers FIRST so planes_t has a ~9MB guard region before it
    // (boundary taps with zeroed weights may read up to ~33KB before a plane).
    char* ws = (char*)d_ws;
    size_t off = 0;
    float* sig_c    = (float*)(ws + off); off += (size_t)NSAMP * 4;
    float* sig_f    = (float*)(ws + off); off += (size_t)NSAMP * 4;
    float* dfine    = (float*)(ws + off); off += (size_t)NSAMP * 4;
    float* w1t      = (float*)(ws + off); off += 64 * 32 * 4;
    float* w2p      = (float*)(ws + off); off += 64 * 36 * 4;
    float* w2s      = (float*)(ws + off); off += 64 * 40 * 4;
    float* bq2      = (float*)(ws + off); off += 256;
    float* planes_t = (float*)(ws + off); off += (size_t)NB * 3 * NH * NW * NC * 4;
    float* rgb_c    = (float*)(ws + off); off += (size_t)NSAMP * 32 * 4;
    float* rgb_f    = (float*)(ws + off); off += (size_t)NSAMP * 32 * 4;

    float* out_rgb = (float*)d_out;
    float* out_dep = out_rgb + (size_t)NRAYS * 32;
    float* out_wt  = out_dep + NRAYS;

    k_prep<<<dim3(1), dim3(256), 0, stream>>>(dw1, dw2, db2, w1t, w2p, w2s, bq2);
    k_transpose<<<dim3(NB * 3 * 1024), dim3(256), 0, stream>>>(planes, planes_t);
    // coarse: gather feats into rgb_c, PAIR MLP in-place (A/B arm 1)
    k_gather<false><<<dim3(NSAMP / 256), dim3(256), 0, stream>>>(
        planes_t, origins, dirs, (const float*)nullptr, rgb_c);
    k_mlp_pair<<<dim3(NSAMP * 2 / 256), dim3(256), 0, stream>>>(
        w1t, db1, w2s, bq2, rgb_c, sig_c);
    k_importance<<<dim3(NRAYS / 256), dim3(256), 0, stream>>>(sig_c, dfine);
    // fine: gather feats into rgb_f, V1 MLP in-place (A/B arm 2, known-good)
    k_gather<true><<<dim3(NSAMP / 256), dim3(256), 0, stream>>>(
        planes_t, origins, dirs, dfine, rgb_f);
    k_mlp<<<dim3(NSAMP / 256), dim3(256), 0, stream>>>(
        w1t, db1, w2p, db2, rgb_f, sig_f);
    k_final<<<dim3(NRAYS / 4), dim3(256), 0, stream>>>(
        sig_c, rgb_c, sig_f, rgb_f, dfine, dirs, z_bg,
        bw1, bb1, bw2, bb2, out_rgb, out_dep, out_wt);
}